// Round 2
// baseline (442.649 us; speedup 1.0000x reference)
//
#include <hip/hip_runtime.h>
#include <hip/hip_bf16.h>

typedef __attribute__((ext_vector_type(8))) short short8;
typedef __attribute__((ext_vector_type(4))) float f32x4;
typedef __attribute__((ext_vector_type(8))) unsigned short ushort8v;

#define AS_GLOBAL __attribute__((address_space(1)))
#define AS_LDS    __attribute__((address_space(3)))

__device__ __forceinline__ void async_ld16(const void* src, void* lds) {
  __builtin_amdgcn_global_load_lds((const AS_GLOBAL unsigned int*)src,
                                   (AS_LDS unsigned int*)lds, 16, 0, 0);
}

__device__ __forceinline__ unsigned short f2bf(float f) {
  unsigned int u = __float_as_uint(f);
  u = (u + 0x7fffu + ((u >> 16) & 1u)) >> 16;
  return (unsigned short)u;
}

// ---------------------------------------------------------------- convert
__global__ void cvt_bf16(const float* __restrict__ x,  const float* __restrict__ wq,
                         const float* __restrict__ wk, const float* __restrict__ wvv,
                         const float* __restrict__ wo,
                         unsigned short* __restrict__ xb,  unsigned short* __restrict__ wqb,
                         unsigned short* __restrict__ wkb, unsigned short* __restrict__ wvb,
                         unsigned short* __restrict__ wob)
{
  const int NX = 8388608, NW = 4194304;
  const int total = (NX + 4 * NW) >> 3;   // 8 floats per item
  for (int v = blockIdx.x * blockDim.x + threadIdx.x; v < total;
       v += gridDim.x * blockDim.x) {
    int base = v << 3;
    const float* src; unsigned short* dst; int off;
    if (base < NX) { src = x; dst = xb; off = base; }
    else {
      int t = base - NX; int w = t >> 22; off = t & (NW - 1);
      src = (w == 0) ? wq : (w == 1) ? wk : (w == 2) ? wvv : wo;
      dst = (w == 0) ? wqb : (w == 1) ? wkb : (w == 2) ? wvb : wob;
    }
    float4 f0 = *(const float4*)(src + off);
    float4 f1 = *(const float4*)(src + off + 4);
    ushort8v o;
    o[0] = f2bf(f0.x); o[1] = f2bf(f0.y); o[2] = f2bf(f0.z); o[3] = f2bf(f0.w);
    o[4] = f2bf(f1.x); o[5] = f2bf(f1.y); o[6] = f2bf(f1.z); o[7] = f2bf(f1.w);
    *(ushort8v*)(dst + off) = o;
  }
}

// ---------------------------------------------------------------- GEMM  C = A * B^T
// A: [M][K] bf16 row-major, B: [N][K] bf16 row-major (so C[i][j] = sum_k A[i,k]*B[j,k])
// MODE 0: bf16 row-major C   MODE 1: RoPE + bf16 row-major C
// MODE 2: bf16 transposed-per-head C -> VT[b][h][d][s]   MODE 3: fp32 row-major C
#define BM 128
#define BN 128
#define BKT 64

template<int MODE>
__global__ __launch_bounds__(256, 3) void gemm_bt(
    const short* __restrict__ A, const short* __restrict__ B,
    void* __restrict__ C, int M, int N, int K,
    const float* __restrict__ pcos, const float* __restrict__ psin)
{
  __shared__ short As[BM * BKT];   // swizzled: byte col ^ ((row&7)<<4), rows of 128B
  __shared__ short Bs[BN * BKT];

  const int tid  = threadIdx.x;
  const int lane = tid & 63;
  const int wv   = tid >> 6;
  const int wr   = (wv >> 1) << 6;
  const int wc   = (wv & 1) << 6;
  const int l15  = lane & 15;
  const int lg   = lane >> 4;

  const int nbn = N >> 7;
  const int nwg = gridDim.x;
  int id = blockIdx.x;
  id = (id & 7) * (nwg >> 3) + (id >> 3);   // XCD swizzle (nwg % 8 == 0)
  const int m0 = (id / nbn) << 7;
  const int n0 = (id % nbn) << 7;

  f32x4 acc[4][4] = {};

  for (int kt = 0; kt < K; kt += BKT) {
    __syncthreads();
#pragma unroll
    for (int i = 0; i < 4; ++i) {
      int c = i * 256 + tid;
      int r = c >> 3;
      int colb = (c & 7) << 4;
      int scol = colb ^ ((r & 7) << 4);
      async_ld16((const char*)A + (((size_t)(m0 + r) * K + kt) << 1) + scol,
                 (char*)As + c * 16);
    }
#pragma unroll
    for (int i = 0; i < 4; ++i) {
      int c = i * 256 + tid;
      int r = c >> 3;
      int colb = (c & 7) << 4;
      int scol = colb ^ ((r & 7) << 4);
      async_ld16((const char*)B + (((size_t)(n0 + r) * K + kt) << 1) + scol,
                 (char*)Bs + c * 16);
    }
    __syncthreads();

#pragma unroll
    for (int kk = 0; kk < 2; ++kk) {
      const int kb = (kk << 6) + (lg << 4);
      short8 af[4], bf[4];
#pragma unroll
      for (int mi = 0; mi < 4; ++mi) {
        int row = wr + (mi << 4) + l15;
        af[mi] = *(const short8*)((const char*)As + (row << 7) + (kb ^ ((row & 7) << 4)));
      }
#pragma unroll
      for (int ni = 0; ni < 4; ++ni) {
        int row = wc + (ni << 4) + l15;
        bf[ni] = *(const short8*)((const char*)Bs + (row << 7) + (kb ^ ((row & 7) << 4)));
      }
#pragma unroll
      for (int mi = 0; mi < 4; ++mi)
#pragma unroll
        for (int ni = 0; ni < 4; ++ni)
          acc[mi][ni] = __builtin_amdgcn_mfma_f32_16x16x32_bf16(
              af[mi], bf[ni], acc[mi][ni], 0, 0, 0);
    }
  }

#pragma unroll
  for (int mi = 0; mi < 4; ++mi) {
#pragma unroll
    for (int ni = 0; ni < 4; ++ni) {
      const int col  = n0 + wc + (ni << 4) + l15;
      const int row0 = m0 + wr + (mi << 4) + (lg << 2);
      if (MODE == 0) {
#pragma unroll
        for (int r = 0; r < 4; ++r)
          ((unsigned short*)C)[(size_t)(row0 + r) * N + col] = f2bf(acc[mi][ni][r]);
      } else if (MODE == 1) {
        const int d = col & 127;
        const int j = d >> 1;
#pragma unroll
        for (int r = 0; r < 4; ++r) {
          int s = (row0 + r) & 2047;
          float cv = pcos[(s << 6) + j];
          float sv = psin[(s << 6) + j];
          float v  = acc[mi][ni][r];
          float pv = __shfl_xor(v, 1, 64);   // partner column (d ^ 1)
          float o  = (d & 1) ? (pv * sv + v * cv) : (v * cv - pv * sv);
          ((unsigned short*)C)[(size_t)(row0 + r) * N + col] = f2bf(o);
        }
      } else if (MODE == 2) {
        const int h = col >> 7, d = col & 127;
        const int b = row0 >> 11, s = row0 & 2047;
        unsigned long long pk =
              (unsigned long long)f2bf(acc[mi][ni][0])
            | ((unsigned long long)f2bf(acc[mi][ni][1]) << 16)
            | ((unsigned long long)f2bf(acc[mi][ni][2]) << 32)
            | ((unsigned long long)f2bf(acc[mi][ni][3]) << 48);
        *(unsigned long long*)((unsigned short*)C +
            (((((size_t)b << 4) + h) << 7) + d) * 2048 + s) = pk;
      } else {
#pragma unroll
        for (int r = 0; r < 4; ++r)
          ((float*)C)[(size_t)(row0 + r) * N + col] = acc[mi][ni][r];
      }
    }
  }
}

// ---------------------------------------------------------------- flash attention
// Q,K: [B*S][2048] bf16 (post-RoPE).  VT: [B][H][128][2048] bf16.  O: [B*S][2048] bf16.
// Block: 4 waves, QBLK=64 (16 q-rows/wave), KVBLK=128, full (non-causal) softmax.
__global__ __launch_bounds__(256, 2) void flash_fwd(
    const short* __restrict__ Q, const short* __restrict__ Kg,
    const short* __restrict__ VT, unsigned short* __restrict__ O)
{
  __shared__ short Ks[128 * 128];      // [kv][d]  rows 256B, swizzled ((row&15)<<4)
  __shared__ short Vs[128 * 128];      // [d][kv]  rows 256B, swizzled
  __shared__ short Ps[4 * 16 * 128];   // per-wave [16 q][128 kv], swizzled

  const int tid  = threadIdx.x;
  const int lane = tid & 63;
  const int wv   = tid >> 6;
  const int l15  = lane & 15;
  const int lg   = lane >> 4;

  const int bh   = blockIdx.y;          // b*16 + h
  const int b    = bh >> 4;
  const int q0   = blockIdx.x << 6;
  const int hcol = (bh & 15) << 7;      // h*128

  short8 qf[4];
  {
    const size_t qoff = ((size_t)((b << 11) + q0 + (wv << 4) + l15) << 11) + hcol;
#pragma unroll
    for (int ks = 0; ks < 4; ++ks)
      qf[ks] = *(const short8*)(Q + qoff + (ks << 5) + (lg << 3));
  }

  f32x4 oacc[8] = {};
  float mrow[4] = {-3e38f, -3e38f, -3e38f, -3e38f};
  float lrow[4] = {0.f, 0.f, 0.f, 0.f};
  const float cl2 = 0.1275313940154099f;   // log2(e)/sqrt(128)

  char* const pbase = (char*)Ps + (wv << 12);

  for (int kv0 = 0; kv0 < 2048; kv0 += 128) {
    __syncthreads();
#pragma unroll
    for (int i = 0; i < 8; ++i) {
      int c = i * 256 + tid;
      int r = c >> 4;
      int colb = (c & 15) << 4;
      int scol = colb ^ ((r & 15) << 4);
      async_ld16((const char*)Kg +
                     (((size_t)((b << 11) + kv0 + r) << 11) + hcol) * 2 + scol,
                 (char*)Ks + c * 16);
    }
#pragma unroll
    for (int i = 0; i < 8; ++i) {
      int c = i * 256 + tid;
      int r = c >> 4;
      int colb = (c & 15) << 4;
      int scol = colb ^ ((r & 15) << 4);
      async_ld16((const char*)VT +
                     (((((size_t)bh << 7) + r) << 11) + kv0) * 2 + scol,
                 (char*)Vs + c * 16);
    }
    __syncthreads();

    // S = Q K^T  (16 q-rows x 128 kv)
    f32x4 sc[8] = {};
#pragma unroll
    for (int ks = 0; ks < 4; ++ks) {
      const int kb = (ks << 6) + (lg << 4);
#pragma unroll
      for (int nt = 0; nt < 8; ++nt) {
        const int row = (nt << 4) + l15;
        short8 kf = *(const short8*)((const char*)Ks + (row << 8) + (kb ^ ((row & 15) << 4)));
        sc[nt] = __builtin_amdgcn_mfma_f32_16x16x32_bf16(qf[ks], kf, sc[nt], 0, 0, 0);
      }
    }

    // online softmax (rows owned by this wave; 16-lane-group shfl reduce)
#pragma unroll
    for (int r = 0; r < 4; ++r) {
      float mx = sc[0][r];
#pragma unroll
      for (int nt = 1; nt < 8; ++nt) mx = fmaxf(mx, sc[nt][r]);
#pragma unroll
      for (int m = 1; m <= 8; m <<= 1) mx = fmaxf(mx, __shfl_xor(mx, m, 64));
      float mnew  = fmaxf(mrow[r], mx);
      float alpha = __builtin_amdgcn_exp2f((mrow[r] - mnew) * cl2);
      mrow[r] = mnew;
      lrow[r] *= alpha;
#pragma unroll
      for (int nt = 0; nt < 8; ++nt) oacc[nt][r] *= alpha;
    }

    float psum[4] = {0.f, 0.f, 0.f, 0.f};
#pragma unroll
    for (int nt = 0; nt < 8; ++nt) {
#pragma unroll
      for (int r = 0; r < 4; ++r) {
        float p = __builtin_amdgcn_exp2f((sc[nt][r] - mrow[r]) * cl2);
        psum[r] += p;
        const int row  = (lg << 2) + r;
        const int colb = ((nt << 4) + l15) << 1;
        *(unsigned short*)(pbase + (row << 8) + (colb ^ ((row & 15) << 4))) = f2bf(p);
      }
    }
#pragma unroll
    for (int r = 0; r < 4; ++r) {
      float s = psum[r];
#pragma unroll
      for (int m = 1; m <= 8; m <<= 1) s += __shfl_xor(s, m, 64);
      lrow[r] += s;
    }

    // O += P V
#pragma unroll
    for (int ks = 0; ks < 4; ++ks) {
      const int kb = (ks << 6) + (lg << 4);
      short8 pf = *(const short8*)(pbase + (l15 << 8) + (kb ^ ((l15 & 15) << 4)));
#pragma unroll
      for (int nt = 0; nt < 8; ++nt) {
        const int row = (nt << 4) + l15;
        short8 vf = *(const short8*)((const char*)Vs + (row << 8) + (kb ^ ((row & 15) << 4)));
        oacc[nt] = __builtin_amdgcn_mfma_f32_16x16x32_bf16(pf, vf, oacc[nt], 0, 0, 0);
      }
    }
  }

  float inv[4];
#pragma unroll
  for (int r = 0; r < 4; ++r) inv[r] = 1.f / lrow[r];
#pragma unroll
  for (int nt = 0; nt < 8; ++nt) {
#pragma unroll
    for (int r = 0; r < 4; ++r) {
      const int srow = q0 + (wv << 4) + (lg << 2) + r;
      O[((size_t)((b << 11) + srow) << 11) + hcol + (nt << 4) + l15] =
          f2bf(oacc[nt][r] * inv[r]);
    }
  }
}

// ---------------------------------------------------------------- launch
extern "C" void kernel_launch(void* const* d_in, const int* in_sizes, int n_in,
                              void* d_out, int out_size, void* d_ws, size_t ws_size,
                              hipStream_t stream)
{
  (void)in_sizes; (void)n_in; (void)out_size; (void)ws_size;
  const float* x    = (const float*)d_in[0];
  const float* wq   = (const float*)d_in[1];
  const float* wk   = (const float*)d_in[2];
  const float* wv   = (const float*)d_in[3];
  const float* wo   = (const float*)d_in[4];
  const float* pcos = (const float*)d_in[5];
  const float* psin = (const float*)d_in[6];

  char* ws = (char*)d_ws;
  short* xb  = (short*)(ws);                  // 16.8 MB  [4096][2048] bf16
  short* wqb = (short*)(ws + 16777216);       //  8.4 MB
  short* wkb = (short*)(ws + 25165824);
  short* wvb = (short*)(ws + 33554432);
  short* wob = (short*)(ws + 41943040);
  short* Qr  = (short*)(ws + 50331648);       // 16.8 MB (RoPE'd)
  short* Kr  = (short*)(ws + 67108864);       // 16.8 MB (RoPE'd)
  short* VT  = (short*)(ws + 83886080);       // 16.8 MB [B][H][128][2048]
  short* At  = xb;                            // alias: xb dead after V GEMM

  cvt_bf16<<<2048, 256, 0, stream>>>(x, wq, wk, wv, wo,
      (unsigned short*)xb, (unsigned short*)wqb, (unsigned short*)wkb,
      (unsigned short*)wvb, (unsigned short*)wob);

  gemm_bt<1><<<512, 256, 0, stream>>>(xb, wqb, Qr, 4096, 2048, 2048, pcos, psin);
  gemm_bt<1><<<512, 256, 0, stream>>>(xb, wkb, Kr, 4096, 2048, 2048, pcos, psin);
  gemm_bt<2><<<512, 256, 0, stream>>>(xb, wvb, VT, 4096, 2048, 2048, nullptr, nullptr);

  flash_fwd<<<dim3(32, 32), 256, 0, stream>>>(Qr, Kr, VT, (unsigned short*)At);

  gemm_bt<3><<<512, 256, 0, stream>>>(At, wob, d_out, 4096, 2048, 2048, nullptr, nullptr);
}

// Round 4
// 379.460 us; speedup vs baseline: 1.1665x; 1.1665x over previous
//
#include <hip/hip_runtime.h>
#include <hip/hip_bf16.h>

typedef __attribute__((ext_vector_type(8))) short short8;
typedef __attribute__((ext_vector_type(4))) float f32x4;
typedef __attribute__((ext_vector_type(16))) float f32x16;
typedef __attribute__((ext_vector_type(8))) unsigned short ushort8v;
typedef __attribute__((ext_vector_type(4))) unsigned int u32x4;

#define AS_GLOBAL __attribute__((address_space(1)))
#define AS_LDS    __attribute__((address_space(3)))

__device__ __forceinline__ void async_ld16(const void* src, void* lds) {
  __builtin_amdgcn_global_load_lds((const AS_GLOBAL unsigned int*)src,
                                   (AS_LDS unsigned int*)lds, 16, 0, 0);
}

__device__ __forceinline__ unsigned short f2bf(float f) {
  unsigned int u = __float_as_uint(f);
  u = (u + 0x7fffu + ((u >> 16) & 1u)) >> 16;
  return (unsigned short)u;
}

// ---------------------------------------------------------------- convert
__global__ void cvt_bf16(const float* __restrict__ x,  const float* __restrict__ wq,
                         const float* __restrict__ wk, const float* __restrict__ wvv,
                         const float* __restrict__ wo,
                         unsigned short* __restrict__ xb,  unsigned short* __restrict__ wqb,
                         unsigned short* __restrict__ wkb, unsigned short* __restrict__ wvb,
                         unsigned short* __restrict__ wob)
{
  const int NX = 8388608, NW = 4194304;
  const int total = (NX + 4 * NW) >> 3;   // 8 floats per item
  for (int v = blockIdx.x * blockDim.x + threadIdx.x; v < total;
       v += gridDim.x * blockDim.x) {
    int base = v << 3;
    const float* src; unsigned short* dst; int off;
    if (base < NX) { src = x; dst = xb; off = base; }
    else {
      int t = base - NX; int w = t >> 22; off = t & (NW - 1);
      src = (w == 0) ? wq : (w == 1) ? wk : (w == 2) ? wvv : wo;
      dst = (w == 0) ? wqb : (w == 1) ? wkb : (w == 2) ? wvb : wob;
    }
    float4 f0 = *(const float4*)(src + off);
    float4 f1 = *(const float4*)(src + off + 4);
    ushort8v o;
    o[0] = f2bf(f0.x); o[1] = f2bf(f0.y); o[2] = f2bf(f0.z); o[3] = f2bf(f0.w);
    o[4] = f2bf(f1.x); o[5] = f2bf(f1.y); o[6] = f2bf(f1.z); o[7] = f2bf(f1.w);
    *(ushort8v*)(dst + off) = o;
  }
}

// ---------------------------------------------------------------- GEMM  C = A * B^T
#define BM 128
#define BN 128
#define BKT 64

template<int MODE>
__global__ __launch_bounds__(256, 3) void gemm_bt(
    const short* __restrict__ A, const short* __restrict__ B,
    void* __restrict__ C, int M, int N, int K,
    const float* __restrict__ pcos, const float* __restrict__ psin)
{
  __shared__ short As[BM * BKT];   // swizzled: byte col ^ ((row&7)<<4)
  __shared__ short Bs[BN * BKT];

  const int tid  = threadIdx.x;
  const int lane = tid & 63;
  const int wv   = tid >> 6;
  const int wr   = (wv >> 1) << 6;
  const int wc   = (wv & 1) << 6;
  const int l15  = lane & 15;
  const int lg   = lane >> 4;

  const int nbn = N >> 7;
  const int nwg = gridDim.x;
  int id = blockIdx.x;
  id = (id & 7) * (nwg >> 3) + (id >> 3);   // XCD swizzle (nwg % 8 == 0)
  const int m0 = (id / nbn) << 7;
  const int n0 = (id % nbn) << 7;

  f32x4 acc[4][4] = {};

  for (int kt = 0; kt < K; kt += BKT) {
    __syncthreads();
#pragma unroll
    for (int i = 0; i < 4; ++i) {
      int c = i * 256 + tid;
      int r = c >> 3;
      int colb = (c & 7) << 4;
      int scol = colb ^ ((r & 7) << 4);
      async_ld16((const char*)A + (((size_t)(m0 + r) * K + kt) << 1) + scol,
                 (char*)As + c * 16);
    }
#pragma unroll
    for (int i = 0; i < 4; ++i) {
      int c = i * 256 + tid;
      int r = c >> 3;
      int colb = (c & 7) << 4;
      int scol = colb ^ ((r & 7) << 4);
      async_ld16((const char*)B + (((size_t)(n0 + r) * K + kt) << 1) + scol,
                 (char*)Bs + c * 16);
    }
    __syncthreads();

#pragma unroll
    for (int kk = 0; kk < 2; ++kk) {
      const int kb = (kk << 6) + (lg << 4);
      short8 af[4], bf[4];
#pragma unroll
      for (int mi = 0; mi < 4; ++mi) {
        int row = wr + (mi << 4) + l15;
        af[mi] = *(const short8*)((const char*)As + (row << 7) + (kb ^ ((row & 7) << 4)));
      }
#pragma unroll
      for (int ni = 0; ni < 4; ++ni) {
        int row = wc + (ni << 4) + l15;
        bf[ni] = *(const short8*)((const char*)Bs + (row << 7) + (kb ^ ((row & 7) << 4)));
      }
#pragma unroll
      for (int mi = 0; mi < 4; ++mi)
#pragma unroll
        for (int ni = 0; ni < 4; ++ni)
          acc[mi][ni] = __builtin_amdgcn_mfma_f32_16x16x32_bf16(
              af[mi], bf[ni], acc[mi][ni], 0, 0, 0);
    }
  }

#pragma unroll
  for (int mi = 0; mi < 4; ++mi) {
#pragma unroll
    for (int ni = 0; ni < 4; ++ni) {
      const int col  = n0 + wc + (ni << 4) + l15;
      const int row0 = m0 + wr + (mi << 4) + (lg << 2);
      if (MODE == 0) {
#pragma unroll
        for (int r = 0; r < 4; ++r)
          ((unsigned short*)C)[(size_t)(row0 + r) * N + col] = f2bf(acc[mi][ni][r]);
      } else if (MODE == 1) {
        const int d = col & 127;
        const int j = d >> 1;
#pragma unroll
        for (int r = 0; r < 4; ++r) {
          int s = (row0 + r) & 2047;
          float cv = pcos[(s << 6) + j];
          float sv = psin[(s << 6) + j];
          float v  = acc[mi][ni][r];
          float pv = __shfl_xor(v, 1, 64);   // partner column (d ^ 1)
          float o  = (d & 1) ? (pv * sv + v * cv) : (v * cv - pv * sv);
          ((unsigned short*)C)[(size_t)(row0 + r) * N + col] = f2bf(o);
        }
      } else if (MODE == 2) {
        const int h = col >> 7, d = col & 127;
        const int b = row0 >> 11, s = row0 & 2047;
        unsigned long long pk =
              (unsigned long long)f2bf(acc[mi][ni][0])
            | ((unsigned long long)f2bf(acc[mi][ni][1]) << 16)
            | ((unsigned long long)f2bf(acc[mi][ni][2]) << 32)
            | ((unsigned long long)f2bf(acc[mi][ni][3]) << 48);
        *(unsigned long long*)((unsigned short*)C +
            (((((size_t)b << 4) + h) << 7) + d) * 2048 + s) = pk;
      } else {
#pragma unroll
        for (int r = 0; r < 4; ++r)
          ((float*)C)[(size_t)(row0 + r) * N + col] = acc[mi][ni][r];
      }
    }
  }
}

// ---------------------------------------------------------------- flash attention v3
// 8 waves x 32 q-rows, KVBLK=64, swapped QK^T (mfma(K,Q)) -> in-register softmax.
// Permlane-free: all cross-half moves via __shfl_xor(.,32).
__global__ __launch_bounds__(512, 2) void flash_fwd2(
    const short* __restrict__ Q, const short* __restrict__ Kg,
    const short* __restrict__ VT, unsigned short* __restrict__ O)
{
  __shared__ short Ks[2][64 * 128];    // [kv][d] rows 256B, swizzle byte^((row&15)<<4)
  __shared__ short Vs[2][128 * 64];    // [d][kv] rows 128B, swizzle byte^((row&7)<<4)

  const int tid = threadIdx.x;
  const int lane = tid & 63;
  const int w   = tid >> 6;
  const int l31 = lane & 31;
  const int hi  = lane >> 5;

  const int bh   = blockIdx.y;
  const int b    = bh >> 4;
  const int q0   = blockIdx.x << 8;          // 256 q-rows per block
  const int hcol = (bh & 15) << 7;

  // Q fragments: B-operand of mfma(K,Q): lane holds q=l31, k=d, octet hi*8
  short8 qf[8];
  {
    const short* qp = Q + (((size_t)((b << 11) + q0 + (w << 5) + l31)) << 11)
                        + hcol + (hi << 3);
#pragma unroll
    for (int dk = 0; dk < 8; ++dk)
      qf[dk] = *(const short8*)(qp + (dk << 4));
  }

  // staging bases (inverse-swizzled global source, linear LDS dest)
  const char* kS0 = (const char*)Kg +
      (((((size_t)(b << 11)) + (tid >> 4)) << 11) + hcol) * 2 +
      (((tid & 15) << 4) ^ (((tid >> 4) & 15) << 4));
  const char* kS1 = (const char*)Kg +
      (((((size_t)(b << 11)) + 32 + (tid >> 4)) << 11) + hcol) * 2 +
      (((tid & 15) << 4) ^ (((tid >> 4) & 15) << 4));
  const char* vS0 = (const char*)VT +
      (((size_t)((bh << 7) + (tid >> 3))) << 12) +
      (((tid & 7) << 4) ^ (((tid >> 3) & 7) << 4));
  const char* vS1 = vS0 + ((size_t)64 << 12);

#define STAGE(t, bf) do {                                              \
    size_t ko = (size_t)(t) * 262144; int vo = (t) * 128;              \
    async_ld16(kS0 + ko, (char*)Ks[bf] + tid * 16);                    \
    async_ld16(kS1 + ko, (char*)Ks[bf] + (tid + 512) * 16);            \
    async_ld16(vS0 + vo, (char*)Vs[bf] + tid * 16);                    \
    async_ld16(vS1 + vo, (char*)Vs[bf] + (tid + 512) * 16);            \
  } while (0)

  f32x16 oacc[4] = {};
  float M = -3e38f, l = 0.f;
  const float cl2 = 0.1275313940154099f;   // log2(e)/sqrt(128)

  STAGE(0, 0);
  int cur = 0;

  const int kxor = (l31 & 15) << 4;

  for (int t = 0; t < 32; ++t) {
    __builtin_amdgcn_s_barrier();            // all waves done reading buf cur^1
    asm volatile("" ::: "memory");
    if (t < 31) {
      STAGE(t + 1, cur ^ 1);
      asm volatile("s_waitcnt vmcnt(4)" ::: "memory");
    } else {
      asm volatile("s_waitcnt vmcnt(0)" ::: "memory");
    }
    __builtin_amdgcn_s_barrier();            // buf cur fully staged
    asm volatile("" ::: "memory");

    const char* kb = (const char*)Ks[cur];
    const char* vb = (const char*)Vs[cur];

    // ---- S^T = K * Q^T : lane holds P[kv-slice][q=l31]
    f32x16 s0 = {}, s1 = {};
#pragma unroll
    for (int dk = 0; dk < 8; ++dk) {
      const int cb = ((dk << 5) + (hi << 4)) ^ kxor;
      short8 kf0 = *(const short8*)(kb + (l31 << 8) + cb);
      short8 kf1 = *(const short8*)(kb + ((32 + l31) << 8) + cb);
      s0 = __builtin_amdgcn_mfma_f32_32x32x16_bf16(kf0, qf[dk], s0, 0, 0, 0);
      s1 = __builtin_amdgcn_mfma_f32_32x32x16_bf16(kf1, qf[dk], s1, 0, 0, 0);
    }

    // ---- online softmax (all in registers; cross-half via shfl_xor 32)
    float tmax = s0[0];
#pragma unroll
    for (int r = 1; r < 16; ++r) tmax = fmaxf(tmax, s0[r]);
#pragma unroll
    for (int r = 0; r < 16; ++r) tmax = fmaxf(tmax, s1[r]);
    tmax = fmaxf(tmax, __shfl_xor(tmax, 32, 64));
    tmax *= cl2;                              // scaled domain
    if (!__all(tmax <= M + 8.f)) {            // defer-max (THR=8)
      float mnew = fmaxf(M, tmax);
      float alpha = __builtin_amdgcn_exp2f(M - mnew);
      M = mnew;
      l *= alpha;
#pragma unroll
      for (int nd = 0; nd < 4; ++nd) oacc[nd] = oacc[nd] * alpha;
    }
    float psum = 0.f;
#pragma unroll
    for (int r = 0; r < 16; ++r) {
      float p = __builtin_amdgcn_exp2f(s0[r] * cl2 - M);
      s0[r] = p; psum += p;
    }
#pragma unroll
    for (int r = 0; r < 16; ++r) {
      float p = __builtin_amdgcn_exp2f(s1[r] * cl2 - M);
      s1[r] = p; psum += p;
    }
    psum += __shfl_xor(psum, 32, 64);
    l += psum;

    // ---- P -> bf16 A-fragments (cvt_pk + shfl_xor(32) + select), O += P*V
#pragma unroll
    for (int ks = 0; ks < 4; ++ks) {
      const int base = (ks & 1) << 3;
      float p0, p1, p2, p3, p4, p5, p6, p7;
      if (ks < 2) {
        p0 = s0[base + 0]; p1 = s0[base + 1]; p2 = s0[base + 2]; p3 = s0[base + 3];
        p4 = s0[base + 4]; p5 = s0[base + 5]; p6 = s0[base + 6]; p7 = s0[base + 7];
      } else {
        p0 = s1[base + 0]; p1 = s1[base + 1]; p2 = s1[base + 2]; p3 = s1[base + 3];
        p4 = s1[base + 4]; p5 = s1[base + 5]; p6 = s1[base + 6]; p7 = s1[base + 7];
      }
      unsigned int X, Y, Z, W;
      asm("v_cvt_pk_bf16_f32 %0, %1, %2" : "=v"(X) : "v"(p0), "v"(p1));
      asm("v_cvt_pk_bf16_f32 %0, %1, %2" : "=v"(Y) : "v"(p2), "v"(p3));
      asm("v_cvt_pk_bf16_f32 %0, %1, %2" : "=v"(Z) : "v"(p4), "v"(p5));
      asm("v_cvt_pk_bf16_f32 %0, %1, %2" : "=v"(W) : "v"(p6), "v"(p7));
      unsigned int SX = (unsigned int)__shfl_xor((int)X, 32, 64);
      unsigned int SY = (unsigned int)__shfl_xor((int)Y, 32, 64);
      unsigned int SZ = (unsigned int)__shfl_xor((int)Z, 32, 64);
      unsigned int SW = (unsigned int)__shfl_xor((int)W, 32, 64);
      // lane-half routing (derived from C-layout crow = (r&3)+8*(r>>2)+4*hi):
      //   hi=0 needs kv[0..7]  = [X, Y, SX, SY]
      //   hi=1 needs kv[8..15] = [SZ, SW, Z, W]
      u32x4 pw;
      pw[0] = hi ? SZ : X;
      pw[1] = hi ? SW : Y;
      pw[2] = hi ? Z  : SX;
      pw[3] = hi ? W  : SY;
      short8 pa = __builtin_bit_cast(short8, pw);
#pragma unroll
      for (int nd = 0; nd < 4; ++nd) {
        const int row = (nd << 5) + l31;
        short8 vf = *(const short8*)(vb + (row << 7) +
                     (((ks << 5) + (hi << 4)) ^ ((row & 7) << 4)));
        oacc[nd] = __builtin_amdgcn_mfma_f32_32x32x16_bf16(pa, vf, oacc[nd], 0, 0, 0);
      }
    }
    cur ^= 1;
  }
#undef STAGE

  // ---- epilogue: normalize and store
  const float linv = 1.f / l;
  float lr[16];
#pragma unroll
  for (int r = 0; r < 16; ++r)
    lr[r] = __shfl(linv, (r & 3) + ((r >> 2) << 3) + (hi << 2), 64);

  const size_t orow0 = (size_t)((b << 11) + q0 + (w << 5));
#pragma unroll
  for (int nd = 0; nd < 4; ++nd) {
#pragma unroll
    for (int r = 0; r < 16; ++r) {
      const int crow = (r & 3) + ((r >> 2) << 3) + (hi << 2);
      O[((orow0 + crow) << 11) + hcol + (nd << 5) + l31] =
          f2bf(oacc[nd][r] * lr[r]);
    }
  }
}

// ---------------------------------------------------------------- launch
extern "C" void kernel_launch(void* const* d_in, const int* in_sizes, int n_in,
                              void* d_out, int out_size, void* d_ws, size_t ws_size,
                              hipStream_t stream)
{
  (void)in_sizes; (void)n_in; (void)out_size; (void)ws_size;
  const float* x    = (const float*)d_in[0];
  const float* wq   = (const float*)d_in[1];
  const float* wk   = (const float*)d_in[2];
  const float* wv   = (const float*)d_in[3];
  const float* wo   = (const float*)d_in[4];
  const float* pcos = (const float*)d_in[5];
  const float* psin = (const float*)d_in[6];

  char* ws = (char*)d_ws;
  short* xb  = (short*)(ws);                  // 16.8 MB  [4096][2048] bf16
  short* wqb = (short*)(ws + 16777216);       //  8.4 MB
  short* wkb = (short*)(ws + 25165824);
  short* wvb = (short*)(ws + 33554432);
  short* wob = (short*)(ws + 41943040);
  short* Qr  = (short*)(ws + 50331648);       // 16.8 MB (RoPE'd)
  short* Kr  = (short*)(ws + 67108864);       // 16.8 MB (RoPE'd)
  short* VT  = (short*)(ws + 83886080);       // 16.8 MB [B][H][128][2048]
  short* At  = xb;                            // alias: xb dead after V GEMM

  cvt_bf16<<<2048, 256, 0, stream>>>(x, wq, wk, wv, wo,
      (unsigned short*)xb, (unsigned short*)wqb, (unsigned short*)wkb,
      (unsigned short*)wvb, (unsigned short*)wob);

  gemm_bt<1><<<512, 256, 0, stream>>>(xb, wqb, Qr, 4096, 2048, 2048, pcos, psin);
  gemm_bt<1><<<512, 256, 0, stream>>>(xb, wkb, Kr, 4096, 2048, 2048, pcos, psin);
  gemm_bt<2><<<512, 256, 0, stream>>>(xb, wvb, VT, 4096, 2048, 2048, nullptr, nullptr);

  flash_fwd2<<<dim3(8, 32), 512, 0, stream>>>(Qr, Kr, VT, (unsigned short*)At);

  gemm_bt<3><<<512, 256, 0, stream>>>(At, wob, d_out, 4096, 2048, 2048, nullptr, nullptr);
}

// Round 5
// 378.357 us; speedup vs baseline: 1.1699x; 1.0029x over previous
//
#include <hip/hip_runtime.h>
#include <hip/hip_bf16.h>

typedef __attribute__((ext_vector_type(8))) short short8;
typedef __attribute__((ext_vector_type(4))) float f32x4;
typedef __attribute__((ext_vector_type(16))) float f32x16;
typedef __attribute__((ext_vector_type(8))) unsigned short ushort8v;
typedef __attribute__((ext_vector_type(4))) unsigned int u32x4;

#define AS_GLOBAL __attribute__((address_space(1)))
#define AS_LDS    __attribute__((address_space(3)))

__device__ __forceinline__ void async_ld16(const void* src, void* lds) {
  __builtin_amdgcn_global_load_lds((const AS_GLOBAL unsigned int*)src,
                                   (AS_LDS unsigned int*)lds, 16, 0, 0);
}

__device__ __forceinline__ unsigned short f2bf(float f) {
  unsigned int u = __float_as_uint(f);
  u = (u + 0x7fffu + ((u >> 16) & 1u)) >> 16;
  return (unsigned short)u;
}

// ---------------------------------------------------------------- convert
__global__ void cvt_bf16(const float* __restrict__ x,  const float* __restrict__ wq,
                         const float* __restrict__ wk, const float* __restrict__ wvv,
                         const float* __restrict__ wo,
                         unsigned short* __restrict__ xb,  unsigned short* __restrict__ wqb,
                         unsigned short* __restrict__ wkb, unsigned short* __restrict__ wvb,
                         unsigned short* __restrict__ wob)
{
  const int NX = 8388608, NW = 4194304;
  const int total = (NX + 4 * NW) >> 3;
  for (int v = blockIdx.x * blockDim.x + threadIdx.x; v < total;
       v += gridDim.x * blockDim.x) {
    int base = v << 3;
    const float* src; unsigned short* dst; int off;
    if (base < NX) { src = x; dst = xb; off = base; }
    else {
      int t = base - NX; int w = t >> 22; off = t & (NW - 1);
      src = (w == 0) ? wq : (w == 1) ? wk : (w == 2) ? wvv : wo;
      dst = (w == 0) ? wqb : (w == 1) ? wkb : (w == 2) ? wvb : wob;
    }
    float4 f0 = *(const float4*)(src + off);
    float4 f1 = *(const float4*)(src + off + 4);
    ushort8v o;
    o[0] = f2bf(f0.x); o[1] = f2bf(f0.y); o[2] = f2bf(f0.z); o[3] = f2bf(f0.w);
    o[4] = f2bf(f1.x); o[5] = f2bf(f1.y); o[6] = f2bf(f1.z); o[7] = f2bf(f1.w);
    *(ushort8v*)(dst + off) = o;
  }
}

// ---------------------------------------------------------------- GEMM v2
// C = A * B^T.  A[M][K], B[N][K] bf16 row-major.
// 256x128 tile, BK=64, 8 waves (4M x 2N), wave tile 64x64, double-buffered LDS,
// 2-phase pipelined K-loop with counted vmcnt (loads stay in flight across barriers).
// MODE 0: fused QKV epilogue (col<4096: RoPE -> Cqk; col>=4096: transpose -> Cvt)
// MODE 1: fp32 C -> Cf
template<int MODE>
__global__ __launch_bounds__(512, 2) void gemm8(
    const short* __restrict__ A, const short* __restrict__ B,
    unsigned short* __restrict__ Cqk, unsigned short* __restrict__ Cvt,
    float* __restrict__ Cf, int M, int N, int K,
    const float* __restrict__ pcos, const float* __restrict__ psin)
{
  // per buffer: A 256x64 bf16 (32KB, rows 128B) then B 128x64 (16KB).
  // swizzle: byte col16 ^ ((row&7)<<4)
  __shared__ short L[2][24576];

  const int tid  = threadIdx.x;
  const int lane = tid & 63;
  const int w    = tid >> 6;
  const int wm   = w >> 1;          // 0..3
  const int wn   = w & 1;           // 0..1
  const int l15  = lane & 15;
  const int lg   = lane >> 4;

  const int nbn = N >> 7;
  const int nwg = gridDim.x;
  int id = blockIdx.x;
  id = (id & 7) * (nwg >> 3) + (id >> 3);     // XCD swizzle (nwg % 8 == 0)
  const int m0 = (id / nbn) << 8;
  const int n0 = (id % nbn) << 7;

  // staging source pointers (inverse-swizzled global, linear LDS dest)
  const char* aS[4];
  const char* bS[2];
#pragma unroll
  for (int i = 0; i < 4; ++i) {
    int c = i * 512 + tid;
    int r = c >> 3;
    int scol = ((c & 7) << 4) ^ ((r & 7) << 4);
    aS[i] = (const char*)A + (((size_t)(m0 + r) * K) << 1) + scol;
  }
#pragma unroll
  for (int i = 0; i < 2; ++i) {
    int c = i * 512 + tid;
    int r = c >> 3;
    int scol = ((c & 7) << 4) ^ ((r & 7) << 4);
    bS[i] = (const char*)B + (((size_t)(n0 + r) * K) << 1) + scol;
  }

#define STAGE_A(t, buf) do {                                            \
    const size_t ko_ = (size_t)(t) << 7;                                \
    _Pragma("unroll")                                                   \
    for (int i_ = 0; i_ < 4; ++i_)                                      \
      async_ld16(aS[i_] + ko_, (char*)L[buf] + (i_ * 512 + tid) * 16);  \
  } while (0)
#define STAGE_B(t, buf) do {                                            \
    const size_t ko_ = (size_t)(t) << 7;                                \
    _Pragma("unroll")                                                   \
    for (int i_ = 0; i_ < 2; ++i_)                                      \
      async_ld16(bS[i_] + ko_,                                          \
                 (char*)L[buf] + 32768 + (i_ * 512 + tid) * 16);        \
  } while (0)

  f32x4 acc[4][4] = {};
  const int T = K >> 6;

  // prologue: stage tile 0 (6 loads/thread outstanding)
  STAGE_A(0, 0);
  STAGE_B(0, 0);

  for (int t = 0; t < T; ++t) {
    const int rb = t & 1, sb = rb ^ 1;
    const char* Lr = (const char*)L[rb];

    // ======== phase 0 ========
    if (t + 1 < T) {
      STAGE_A(t + 1, sb);                       // +4 loads (tile t+1 A)
      asm volatile("s_waitcnt vmcnt(4)" ::: "memory");  // tile-t's 6 retired
    } else {
      asm volatile("s_waitcnt vmcnt(0)" ::: "memory");
    }
    __builtin_amdgcn_s_barrier();               // all waves' tile-t staging done
    asm volatile("" ::: "memory");

    short8 af[4][2], bf[2][2];
#pragma unroll
    for (int mi = 0; mi < 4; ++mi) {
      const int ra = (wm << 6) + (mi << 4) + l15;
      const int sx = (ra & 7) << 4;
      af[mi][0] = *(const short8*)(Lr + (ra << 7) + ((lg << 4) ^ sx));
      af[mi][1] = *(const short8*)(Lr + (ra << 7) + ((64 + (lg << 4)) ^ sx));
    }
#pragma unroll
    for (int nj = 0; nj < 2; ++nj) {
      const int rn = (wn << 6) + (nj << 4) + l15;
      const int sx = (rn & 7) << 4;
      bf[nj][0] = *(const short8*)(Lr + 32768 + (rn << 7) + ((lg << 4) ^ sx));
      bf[nj][1] = *(const short8*)(Lr + 32768 + (rn << 7) + ((64 + (lg << 4)) ^ sx));
    }
    __builtin_amdgcn_s_setprio(1);
#pragma unroll
    for (int mi = 0; mi < 4; ++mi)
#pragma unroll
      for (int nj = 0; nj < 2; ++nj) {
        acc[mi][nj] = __builtin_amdgcn_mfma_f32_16x16x32_bf16(
            af[mi][0], bf[nj][0], acc[mi][nj], 0, 0, 0);
        acc[mi][nj] = __builtin_amdgcn_mfma_f32_16x16x32_bf16(
            af[mi][1], bf[nj][1], acc[mi][nj], 0, 0, 0);
      }
    __builtin_amdgcn_s_setprio(0);
    __builtin_amdgcn_s_barrier();
    asm volatile("" ::: "memory");

    // ======== phase 1 ========
    if (t + 1 < T) STAGE_B(t + 1, sb);          // +2 loads (tile t+1 B)
#pragma unroll
    for (int nj = 0; nj < 2; ++nj) {
      const int rn = (wn << 6) + ((nj + 2) << 4) + l15;
      const int sx = (rn & 7) << 4;
      bf[nj][0] = *(const short8*)(Lr + 32768 + (rn << 7) + ((lg << 4) ^ sx));
      bf[nj][1] = *(const short8*)(Lr + 32768 + (rn << 7) + ((64 + (lg << 4)) ^ sx));
    }
    __builtin_amdgcn_s_setprio(1);
#pragma unroll
    for (int mi = 0; mi < 4; ++mi)
#pragma unroll
      for (int nj = 0; nj < 2; ++nj) {
        acc[mi][nj + 2] = __builtin_amdgcn_mfma_f32_16x16x32_bf16(
            af[mi][0], bf[nj][0], acc[mi][nj + 2], 0, 0, 0);
        acc[mi][nj + 2] = __builtin_amdgcn_mfma_f32_16x16x32_bf16(
            af[mi][1], bf[nj][1], acc[mi][nj + 2], 0, 0, 0);
      }
    __builtin_amdgcn_s_setprio(0);
    __builtin_amdgcn_s_barrier();               // tile boundary: reads of rb done
    asm volatile("" ::: "memory");
  }
#undef STAGE_A
#undef STAGE_B

  // ---- epilogue
#pragma unroll
  for (int mi = 0; mi < 4; ++mi) {
#pragma unroll
    for (int ni = 0; ni < 4; ++ni) {
      const int col  = n0 + (wn << 6) + (ni << 4) + l15;
      const int row0 = m0 + (wm << 6) + (mi << 4) + (lg << 2);
      if (MODE == 1) {
#pragma unroll
        for (int r = 0; r < 4; ++r)
          Cf[(size_t)(row0 + r) * N + col] = acc[mi][ni][r];
      } else if (col < 4096) {                  // Q / K with RoPE
        const int d = col & 127;
        const int j = d >> 1;
        unsigned short* dst = Cqk + ((size_t)(col >> 11) << 23);
#pragma unroll
        for (int r = 0; r < 4; ++r) {
          int s = (row0 + r) & 2047;
          float cv = pcos[(s << 6) + j];
          float sv = psin[(s << 6) + j];
          float v  = acc[mi][ni][r];
          float pv = __shfl_xor(v, 1, 64);      // partner column (d ^ 1)
          float o  = (d & 1) ? (pv * sv + v * cv) : (v * cv - pv * sv);
          dst[((size_t)(row0 + r) << 11) + (col & 2047)] = f2bf(o);
        }
      } else {                                  // V -> VT[b][h][d][s]
        const int vc = col & 2047;
        const int h = vc >> 7, d = vc & 127;
        const int b = row0 >> 11, s = row0 & 2047;
        unsigned long long pk =
              (unsigned long long)f2bf(acc[mi][ni][0])
            | ((unsigned long long)f2bf(acc[mi][ni][1]) << 16)
            | ((unsigned long long)f2bf(acc[mi][ni][2]) << 32)
            | ((unsigned long long)f2bf(acc[mi][ni][3]) << 48);
        *(unsigned long long*)(Cvt +
            (((((size_t)b << 4) + h) << 7) + d) * 2048 + s) = pk;
      }
    }
  }
}

// ---------------------------------------------------------------- flash attention
// 8 waves x 32 q-rows, KVBLK=64, swapped QK^T (mfma(K,Q)) -> in-register softmax.
__global__ __launch_bounds__(512, 2) void flash_fwd2(
    const short* __restrict__ Q, const short* __restrict__ Kg,
    const short* __restrict__ VT, unsigned short* __restrict__ O)
{
  __shared__ short Ks[2][64 * 128];    // [kv][d] rows 256B, swizzle byte^((row&15)<<4)
  __shared__ short Vs[2][128 * 64];    // [d][kv] rows 128B, swizzle byte^((row&7)<<4)

  const int tid = threadIdx.x;
  const int lane = tid & 63;
  const int w   = tid >> 6;
  const int l31 = lane & 31;
  const int hi  = lane >> 5;

  const int bh   = blockIdx.y;
  const int b    = bh >> 4;
  const int q0   = blockIdx.x << 8;          // 256 q-rows per block
  const int hcol = (bh & 15) << 7;

  short8 qf[8];
  {
    const short* qp = Q + (((size_t)((b << 11) + q0 + (w << 5) + l31)) << 11)
                        + hcol + (hi << 3);
#pragma unroll
    for (int dk = 0; dk < 8; ++dk)
      qf[dk] = *(const short8*)(qp + (dk << 4));
  }

  const char* kS0 = (const char*)Kg +
      (((((size_t)(b << 11)) + (tid >> 4)) << 11) + hcol) * 2 +
      (((tid & 15) << 4) ^ (((tid >> 4) & 15) << 4));
  const char* kS1 = (const char*)Kg +
      (((((size_t)(b << 11)) + 32 + (tid >> 4)) << 11) + hcol) * 2 +
      (((tid & 15) << 4) ^ (((tid >> 4) & 15) << 4));
  const char* vS0 = (const char*)VT +
      (((size_t)((bh << 7) + (tid >> 3))) << 12) +
      (((tid & 7) << 4) ^ (((tid >> 3) & 7) << 4));
  const char* vS1 = vS0 + ((size_t)64 << 12);

#define STAGE(t, bf) do {                                              \
    size_t ko = (size_t)(t) * 262144; int vo = (t) * 128;              \
    async_ld16(kS0 + ko, (char*)Ks[bf] + tid * 16);                    \
    async_ld16(kS1 + ko, (char*)Ks[bf] + (tid + 512) * 16);            \
    async_ld16(vS0 + vo, (char*)Vs[bf] + tid * 16);                    \
    async_ld16(vS1 + vo, (char*)Vs[bf] + (tid + 512) * 16);            \
  } while (0)

  f32x16 oacc[4] = {};
  float M = -3e38f, l = 0.f;
  const float cl2 = 0.1275313940154099f;   // log2(e)/sqrt(128)

  STAGE(0, 0);
  int cur = 0;

  const int kxor = (l31 & 15) << 4;

  for (int t = 0; t < 32; ++t) {
    __builtin_amdgcn_s_barrier();
    asm volatile("" ::: "memory");
    if (t < 31) {
      STAGE(t + 1, cur ^ 1);
      asm volatile("s_waitcnt vmcnt(4)" ::: "memory");
    } else {
      asm volatile("s_waitcnt vmcnt(0)" ::: "memory");
    }
    __builtin_amdgcn_s_barrier();
    asm volatile("" ::: "memory");

    const char* kb = (const char*)Ks[cur];
    const char* vb = (const char*)Vs[cur];

    f32x16 s0 = {}, s1 = {};
#pragma unroll
    for (int dk = 0; dk < 8; ++dk) {
      const int cb = ((dk << 5) + (hi << 4)) ^ kxor;
      short8 kf0 = *(const short8*)(kb + (l31 << 8) + cb);
      short8 kf1 = *(const short8*)(kb + ((32 + l31) << 8) + cb);
      s0 = __builtin_amdgcn_mfma_f32_32x32x16_bf16(kf0, qf[dk], s0, 0, 0, 0);
      s1 = __builtin_amdgcn_mfma_f32_32x32x16_bf16(kf1, qf[dk], s1, 0, 0, 0);
    }

    float tmax = s0[0];
#pragma unroll
    for (int r = 1; r < 16; ++r) tmax = fmaxf(tmax, s0[r]);
#pragma unroll
    for (int r = 0; r < 16; ++r) tmax = fmaxf(tmax, s1[r]);
    tmax = fmaxf(tmax, __shfl_xor(tmax, 32, 64));
    tmax *= cl2;
    if (!__all(tmax <= M + 8.f)) {
      float mnew = fmaxf(M, tmax);
      float alpha = __builtin_amdgcn_exp2f(M - mnew);
      M = mnew;
      l *= alpha;
#pragma unroll
      for (int nd = 0; nd < 4; ++nd) oacc[nd] = oacc[nd] * alpha;
    }
    float psum = 0.f;
#pragma unroll
    for (int r = 0; r < 16; ++r) {
      float p = __builtin_amdgcn_exp2f(s0[r] * cl2 - M);
      s0[r] = p; psum += p;
    }
#pragma unroll
    for (int r = 0; r < 16; ++r) {
      float p = __builtin_amdgcn_exp2f(s1[r] * cl2 - M);
      s1[r] = p; psum += p;
    }
    psum += __shfl_xor(psum, 32, 64);
    l += psum;

#pragma unroll
    for (int ks = 0; ks < 4; ++ks) {
      const int base = (ks & 1) << 3;
      float p0, p1, p2, p3, p4, p5, p6, p7;
      if (ks < 2) {
        p0 = s0[base + 0]; p1 = s0[base + 1]; p2 = s0[base + 2]; p3 = s0[base + 3];
        p4 = s0[base + 4]; p5 = s0[base + 5]; p6 = s0[base + 6]; p7 = s0[base + 7];
      } else {
        p0 = s1[base + 0]; p1 = s1[base + 1]; p2 = s1[base + 2]; p3 = s1[base + 3];
        p4 = s1[base + 4]; p5 = s1[base + 5]; p6 = s1[base + 6]; p7 = s1[base + 7];
      }
      unsigned int X, Y, Z, W;
      asm("v_cvt_pk_bf16_f32 %0, %1, %2" : "=v"(X) : "v"(p0), "v"(p1));
      asm("v_cvt_pk_bf16_f32 %0, %1, %2" : "=v"(Y) : "v"(p2), "v"(p3));
      asm("v_cvt_pk_bf16_f32 %0, %1, %2" : "=v"(Z) : "v"(p4), "v"(p5));
      asm("v_cvt_pk_bf16_f32 %0, %1, %2" : "=v"(W) : "v"(p6), "v"(p7));
      unsigned int SX = (unsigned int)__shfl_xor((int)X, 32, 64);
      unsigned int SY = (unsigned int)__shfl_xor((int)Y, 32, 64);
      unsigned int SZ = (unsigned int)__shfl_xor((int)Z, 32, 64);
      unsigned int SW = (unsigned int)__shfl_xor((int)W, 32, 64);
      u32x4 pw;
      pw[0] = hi ? SZ : X;
      pw[1] = hi ? SW : Y;
      pw[2] = hi ? Z  : SX;
      pw[3] = hi ? W  : SY;
      short8 pa = __builtin_bit_cast(short8, pw);
#pragma unroll
      for (int nd = 0; nd < 4; ++nd) {
        const int row = (nd << 5) + l31;
        short8 vf = *(const short8*)(vb + (row << 7) +
                     (((ks << 5) + (hi << 4)) ^ ((row & 7) << 4)));
        oacc[nd] = __builtin_amdgcn_mfma_f32_32x32x16_bf16(pa, vf, oacc[nd], 0, 0, 0);
      }
    }
    cur ^= 1;
  }
#undef STAGE

  const float linv = 1.f / l;
  float lr[16];
#pragma unroll
  for (int r = 0; r < 16; ++r)
    lr[r] = __shfl(linv, (r & 3) + ((r >> 2) << 3) + (hi << 2), 64);

  const size_t orow0 = (size_t)((b << 11) + q0 + (w << 5));
#pragma unroll
  for (int nd = 0; nd < 4; ++nd) {
#pragma unroll
    for (int r = 0; r < 16; ++r) {
      const int crow = (r & 3) + ((r >> 2) << 3) + (hi << 2);
      O[((orow0 + crow) << 11) + hcol + (nd << 5) + l31] =
          f2bf(oacc[nd][r] * lr[r]);
    }
  }
}

// ---------------------------------------------------------------- launch
extern "C" void kernel_launch(void* const* d_in, const int* in_sizes, int n_in,
                              void* d_out, int out_size, void* d_ws, size_t ws_size,
                              hipStream_t stream)
{
  (void)in_sizes; (void)n_in; (void)out_size; (void)ws_size;
  const float* x    = (const float*)d_in[0];
  const float* wq   = (const float*)d_in[1];
  const float* wk   = (const float*)d_in[2];
  const float* wv   = (const float*)d_in[3];
  const float* wo   = (const float*)d_in[4];
  const float* pcos = (const float*)d_in[5];
  const float* psin = (const float*)d_in[6];

  char* ws = (char*)d_ws;
  short* xb  = (short*)(ws);                  // [4096][2048] bf16
  short* wqb = (short*)(ws + 16777216);       // stacked B: wq/wk/wv contiguous
  short* wkb = (short*)(ws + 25165824);
  short* wvb = (short*)(ws + 33554432);
  short* wob = (short*)(ws + 41943040);
  short* Qr  = (short*)(ws + 50331648);       // Qr then Kr contiguous
  short* Kr  = (short*)(ws + 67108864);
  short* VT  = (short*)(ws + 83886080);       // [B][H][128][2048]
  short* At  = xb;                            // alias: xb dead after QKV GEMM

  cvt_bf16<<<2048, 256, 0, stream>>>(x, wq, wk, wv, wo,
      (unsigned short*)xb, (unsigned short*)wqb, (unsigned short*)wkb,
      (unsigned short*)wvb, (unsigned short*)wob);

  // fused QKV: B = stacked [6144][2048], epilogue routes per column segment
  gemm8<0><<<768, 512, 0, stream>>>(xb, wqb,
      (unsigned short*)Qr, (unsigned short*)VT, nullptr,
      4096, 6144, 2048, pcos, psin);

  flash_fwd2<<<dim3(8, 32), 512, 0, stream>>>(Qr, Kr, VT, (unsigned short*)At);

  gemm8<1><<<256, 512, 0, stream>>>(At, wob,
      nullptr, nullptr, (float*)d_out,
      4096, 2048, 2048, nullptr, nullptr);
}